// Round 3
// baseline (782.334 us; speedup 1.0000x reference)
//
#include <hip/hip_runtime.h>
#include <hip/hip_bf16.h>
#include <stdint.h>

// MLA forward: B=2,S=2048,H=2048,NH=16,D=128,LAT=512.
// R3: runtime input-dtype detection (fp32 vs bf16 device buffers) + fp32-capable
// I/O paths. Internal compute: bf16 MFMA, conservative LDS staging (from R2).
typedef __hip_bfloat16 bf16;
typedef __attribute__((ext_vector_type(8))) short s8v;   // 8 x bf16 (4 VGPRs)
typedef __attribute__((ext_vector_type(4))) float f4v;   // MFMA 16x16 accum

__device__ __forceinline__ f4v mfma16(s8v a, s8v b, f4v c) {
  return __builtin_amdgcn_mfma_f32_16x16x32_bf16(a, b, c, 0, 0, 0);
}

__device__ __forceinline__ unsigned short f2bfu(float f) {
  union { bf16 h; unsigned short u; } cv;
  cv.h = __float2bfloat16(f);
  return cv.u;
}

// ------------- dtype detect: fp32 data read as bf16 has wild exponents -------------
__global__ void detect_dtype(const void* __restrict__ hs, int* __restrict__ flag) {
  if (threadIdx.x != 0) return;
  const unsigned short* u = (const unsigned short*)hs;
  int big = 0;
  for (int i = 0; i < 2048; i++) {
    unsigned short e = (u[i] >> 7) & 0xFF;
    if (e > 133) big++;  // |v| >= 64 impossible for N(0,1) bf16 data
  }
  *flag = (big > 64) ? 1 : 0;  // 1 => buffers hold fp32
}

// ------------- hs convert: (fp32|bf16) -> bf16, 8 elems/thread -------------
__global__ void convert_hs(const void* __restrict__ in, bf16* __restrict__ out,
                           const int* __restrict__ flag, int n) {
  int i = (blockIdx.x * 256 + threadIdx.x) * 8;
  if (i >= n) return;
  if (*flag) {
    const float* f = (const float*)in;
    union { s8v v; unsigned short u[8]; } pk;
#pragma unroll
    for (int j = 0; j < 8; j++) pk.u[j] = f2bfu(f[i + j]);
    *(s8v*)(out + i) = pk.v;
  } else {
    *(s8v*)(out + i) = *(const s8v*)((const bf16*)in + i);
  }
}

// ------------- bias convert: (fp32|bf16) -> fp32 -------------
__global__ void convert_bias(const void* __restrict__ in, float* __restrict__ out,
                             const int* __restrict__ flag, int n) {
  int i = blockIdx.x * 256 + threadIdx.x;
  if (i >= n) return;
  out[i] = (*flag) ? ((const float*)in)[i]
                   : __bfloat162float(((const bf16*)in)[i]);
}

// ------------- weight transpose: in (R x C, fp32|bf16) -> out (C x R, bf16) -------------
__global__ void transpose_any(const void* __restrict__ in, bf16* __restrict__ out,
                              int R, int C, const int* __restrict__ flag) {
  __shared__ float t[32][33];
  int tx = threadIdx.x & 31, ty = threadIdx.x >> 5;  // 256 thr: 32x8
  int c0 = blockIdx.x * 32, r0 = blockIdx.y * 32;
  bool f32 = (*flag != 0);
#pragma unroll
  for (int i = 0; i < 32; i += 8) {
    size_t src = (size_t)(r0 + ty + i) * C + c0 + tx;
    t[ty + i][tx] = f32 ? ((const float*)in)[src]
                        : __bfloat162float(((const bf16*)in)[src]);
  }
  __syncthreads();
#pragma unroll
  for (int i = 0; i < 32; i += 8)
    out[(size_t)(c0 + ty + i) * R + r0 + tx] = __float2bfloat16(t[tx][ty + i]);
}

// ---------------- rope: (4096 x 128) bf16 -> bf16 ----------------
__global__ void rope_kernel(const bf16* __restrict__ in, bf16* __restrict__ out) {
  int row = blockIdx.x;       // b*2048 + s
  int d = threadIdx.x;        // 0..63
  int pos = row & 2047;
  float x1 = __bfloat162float(in[(size_t)row * 128 + d]);
  float x2 = __bfloat162float(in[(size_t)row * 128 + 64 + d]);
  float inv = exp2f(-(float)d * (13.287712379549449f / 64.0f));  // 10000^(-d/64)
  float ang = (float)pos * inv;
  float sn = sinf(ang), cs = cosf(ang);
  out[(size_t)row * 128 + d]      = __float2bfloat16(x1 * cs - x2 * sn);
  out[(size_t)row * 128 + 64 + d] = __float2bfloat16(x1 * sn + x2 * cs);
}

// ---------------- GEMM: C(MxN) = A(MxK) @ Bt(NxK)^T + bias ----------------
// 128x128 tile, BK=32, 4 waves (2x2). Explicit VGPR-roundtrip staging.
// VT=1: write output as vT[(b*16+h)*128+d][s] (per-head transposed V).
// OUTX=1: C is void*; write fp32 if *flag else bf16 (external output).
template <int VT, int OUTX>
__global__ __launch_bounds__(256) void gemm_bt(
    const bf16* __restrict__ A, const bf16* __restrict__ Bt,
    const float* __restrict__ bias, void* __restrict__ Cv,
    int M, int N, int K, const int* __restrict__ flag) {
  __shared__ bf16 sA[128 * 32];
  __shared__ bf16 sB[128 * 32];
  const int tid = threadIdx.x, lane = tid & 63, wid = tid >> 6;
  const int l15 = lane & 15, l4 = lane >> 4;
  const int m0 = blockIdx.y * 128, n0 = blockIdx.x * 128;
  const int wm = (wid >> 1) * 64, wn = (wid & 1) * 64;
  f4v acc[4][4] = {};
  const bf16* gA = A + (size_t)m0 * K;
  const bf16* gB = Bt + (size_t)n0 * K;
  const int row = tid >> 2, col = (tid & 3) * 8;
  for (int k0 = 0; k0 < K; k0 += 32) {
    s8v va0 = *(const s8v*)(gA + (size_t)row * K + k0 + col);
    s8v va1 = *(const s8v*)(gA + (size_t)(row + 64) * K + k0 + col);
    s8v vb0 = *(const s8v*)(gB + (size_t)row * K + k0 + col);
    s8v vb1 = *(const s8v*)(gB + (size_t)(row + 64) * K + k0 + col);
    *(s8v*)(sA + (size_t)tid * 8)         = va0;
    *(s8v*)(sA + (size_t)(tid + 256) * 8) = va1;
    *(s8v*)(sB + (size_t)tid * 8)         = vb0;
    *(s8v*)(sB + (size_t)(tid + 256) * 8) = vb1;
    __syncthreads();
    s8v a[4], b[4];
#pragma unroll
    for (int i = 0; i < 4; i++) a[i] = *(const s8v*)(sA + (wm + i * 16 + l15) * 32 + l4 * 8);
#pragma unroll
    for (int j = 0; j < 4; j++) b[j] = *(const s8v*)(sB + (wn + j * 16 + l15) * 32 + l4 * 8);
#pragma unroll
    for (int i = 0; i < 4; i++)
#pragma unroll
      for (int j = 0; j < 4; j++) acc[i][j] = mfma16(a[i], b[j], acc[i][j]);
    __syncthreads();
  }
  // epilogue. C/D layout: row = l4*4+g, col = l15 (within 16x16 tile)
  if (VT == 0) {
    bool f32o = (OUTX == 1) && (*flag != 0);
#pragma unroll
    for (int j = 0; j < 4; j++) {
      int n = n0 + wn + j * 16 + l15;
      float bv = bias[n];
#pragma unroll
      for (int i = 0; i < 4; i++) {
        size_t mb = m0 + wm + i * 16 + l4 * 4;
#pragma unroll
        for (int g = 0; g < 4; g++) {
          float val = acc[i][j][g] + bv;
          size_t idx = (mb + g) * (size_t)N + n;
          if (OUTX == 1 && f32o) ((float*)Cv)[idx] = val;
          else                   ((bf16*)Cv)[idx] = __float2bfloat16(val);
        }
      }
    }
  } else {
    // vT: n -> (h = n>>7, d = n&127); m -> (b = m>>11, s = m&2047)
    bf16* C = (bf16*)Cv;
#pragma unroll
    for (int j = 0; j < 4; j++) {
      int n = n0 + wn + j * 16 + l15;
      float bv = bias[n];
      int hh = n >> 7, dd = n & 127;
#pragma unroll
      for (int i = 0; i < 4; i++) {
        int m = m0 + wm + i * 16 + l4 * 4;
        int bb = m >> 11, ss = m & 2047;
        unsigned int lo = f2bfu(acc[i][j][0] + bv) | ((unsigned int)f2bfu(acc[i][j][1] + bv) << 16);
        unsigned int hi = f2bfu(acc[i][j][2] + bv) | ((unsigned int)f2bfu(acc[i][j][3] + bv) << 16);
        size_t dst = ((size_t)(bb * 16 + hh) * 128 + dd) * 2048 + ss;
        uint2 pk; pk.x = lo; pk.y = hi;
        *reinterpret_cast<uint2*>(C + dst) = pk;
      }
    }
  }
}

// ---------------- flash attention ----------------
// grid (S/128, B*NH), 256 thr (4 waves; wave owns 32 q-rows).
// LDS: sK/sKr = [dchunk(16)][key(64)][8], sVT = [keychunk(8)][d(128)][8]
__global__ __launch_bounds__(256, 2) void flash_attn(
    const bf16* __restrict__ Qc, const bf16* __restrict__ Kc,
    const bf16* __restrict__ Qr, const bf16* __restrict__ Kr,
    const bf16* __restrict__ VT, const int* __restrict__ amask,
    bf16* __restrict__ ctx) {
  const int S = 2048, H = 2048, D = 128;
  __shared__ bf16 sK[16 * 64 * 8];
  __shared__ bf16 sKr[16 * 64 * 8];
  __shared__ bf16 sVT[8 * 128 * 8];
  __shared__ bf16 sP[4][8 * 32 * 8];  // per-wave P: [kchunk(8)][q(32)][8]

  const int tid = threadIdx.x, lane = tid & 63, wid = tid >> 6;
  const int l15 = lane & 15, l4 = lane >> 4;
  const int qt = blockIdx.x, bh = blockIdx.y;
  const int b = bh >> 4, h = bh & 15;
  const size_t bS = (size_t)b * S;
  const int q0 = qt * 128 + wid * 32;

  // Q fragments in registers (A-operand: m=l15, k=l4*8+j)
  s8v qcf[2][4], qrf[2][4];
#pragma unroll
  for (int r = 0; r < 2; r++) {
    size_t qrow = bS + q0 + r * 16 + l15;
    const bf16* pc = Qc + qrow * H + h * D + l4 * 8;
    const bf16* pr = Qr + qrow * D + l4 * 8;
#pragma unroll
    for (int t = 0; t < 4; t++) {
      qcf[r][t] = *(const s8v*)(pc + t * 32);
      qrf[r][t] = *(const s8v*)(pr + t * 32);
    }
  }

  f4v oacc[2][8] = {};
  float mrow[2][4], lrow[2][4];
#pragma unroll
  for (int r = 0; r < 2; r++)
#pragma unroll
    for (int g = 0; g < 4; g++) { mrow[r][g] = -1e30f; lrow[r][g] = 0.f; }

  const float scl = 0.08838834764831845f;  // 1/sqrt(128)

  for (int kv0 = 0; kv0 < S; kv0 += 64) {
#pragma unroll
    for (int p = 0; p < 4; p++) {
      int idx = tid + p * 256;
      int key = idx & 63, dch = idx >> 6;
      s8v vk  = *(const s8v*)(Kc + (bS + kv0 + key) * H + h * D + dch * 8);
      s8v vkr = *(const s8v*)(Kr + (bS + kv0 + key) * D + dch * 8);
      int d = idx & 127, kch = idx >> 7;
      s8v vv  = *(const s8v*)(VT + ((size_t)bh * D + d) * S + kv0 + kch * 8);
      *(s8v*)(sK  + (size_t)idx * 8) = vk;
      *(s8v*)(sKr + (size_t)idx * 8) = vkr;
      *(s8v*)(sVT + (size_t)idx * 8) = vv;
    }
    __syncthreads();

    int mv[4];
#pragma unroll
    for (int c = 0; c < 4; c++) mv[c] = amask[bS + kv0 + c * 16 + l15];

    // S = Qc.Kc^T + Qr.Kr^T
    f4v sc[2][4] = {};
#pragma unroll
    for (int c = 0; c < 4; c++) {
#pragma unroll
      for (int t = 0; t < 4; t++) {
        s8v kf = *(const s8v*)(sK + ((t * 4 + l4) * 64 + c * 16 + l15) * 8);
        sc[0][c] = mfma16(qcf[0][t], kf, sc[0][c]);
        sc[1][c] = mfma16(qcf[1][t], kf, sc[1][c]);
      }
#pragma unroll
      for (int t = 0; t < 4; t++) {
        s8v kf = *(const s8v*)(sKr + ((t * 4 + l4) * 64 + c * 16 + l15) * 8);
        sc[0][c] = mfma16(qrf[0][t], kf, sc[0][c]);
        sc[1][c] = mfma16(qrf[1][t], kf, sc[1][c]);
      }
    }

    // online softmax (fp32); row = l4*4+g, col = c*16+l15
#pragma unroll
    for (int r = 0; r < 2; r++) {
#pragma unroll
      for (int g = 0; g < 4; g++) {
        float v[4];
#pragma unroll
        for (int c = 0; c < 4; c++) {
          float x = sc[r][c][g] * scl;
          v[c] = (mv[c] == 0) ? -1e30f : x;
        }
        float mx = fmaxf(fmaxf(v[0], v[1]), fmaxf(v[2], v[3]));
#pragma unroll
        for (int off = 8; off; off >>= 1) mx = fmaxf(mx, __shfl_xor(mx, off, 64));
        float mn = fmaxf(mrow[r][g], mx);
        float alpha = __expf(mrow[r][g] - mn);
        mrow[r][g] = mn;
        float ps = 0.f;
        float pv[4];
#pragma unroll
        for (int c = 0; c < 4; c++) { pv[c] = __expf(v[c] - mn); ps += pv[c]; }
#pragma unroll
        for (int off = 8; off; off >>= 1) ps += __shfl_xor(ps, off, 64);
        lrow[r][g] = lrow[r][g] * alpha + ps;
#pragma unroll
        for (int c = 0; c < 8; c++) oacc[r][c][g] *= alpha;
        int qr_ = r * 16 + l4 * 4 + g;
#pragma unroll
        for (int c = 0; c < 4; c++) {
          int kch = 2 * c + (l15 >> 3);
          sP[wid][(kch * 32 + qr_) * 8 + (l15 & 7)] = __float2bfloat16(pv[c]);
        }
      }
    }
    __syncthreads();

    // O += P @ V
#pragma unroll
    for (int t = 0; t < 2; t++) {
      s8v pf0 = *(const s8v*)(sP[wid] + ((t * 4 + l4) * 32 + 0 + l15) * 8);
      s8v pf1 = *(const s8v*)(sP[wid] + ((t * 4 + l4) * 32 + 16 + l15) * 8);
#pragma unroll
      for (int c = 0; c < 8; c++) {
        s8v vf = *(const s8v*)(sVT + ((t * 4 + l4) * 128 + c * 16 + l15) * 8);
        oacc[0][c] = mfma16(pf0, vf, oacc[0][c]);
        oacc[1][c] = mfma16(pf1, vf, oacc[1][c]);
      }
    }
    __syncthreads();
  }

  // normalize + store ctx (B,S,H)
#pragma unroll
  for (int r = 0; r < 2; r++) {
#pragma unroll
    for (int c = 0; c < 8; c++) {
#pragma unroll
      for (int g = 0; g < 4; g++) {
        int qrow = q0 + r * 16 + l4 * 4 + g;
        float val = oacc[r][c][g] / lrow[r][g];
        ctx[(bS + qrow) * H + h * D + c * 16 + l15] = __float2bfloat16(val);
      }
    }
  }
}

// ---------------- launch ----------------
extern "C" void kernel_launch(void* const* d_in, const int* in_sizes, int n_in,
                              void* d_out, int out_size, void* d_ws, size_t ws_size,
                              hipStream_t stream) {
  const void* hs    = d_in[0];
  const int*  amask = (const int*)d_in[1];
  const void* W_DKV = d_in[2];  const void* b_DKV = d_in[3];
  const void* W_DQ  = d_in[4];  const void* b_DQ  = d_in[5];
  const void* W_UK  = d_in[6];  const void* b_UK  = d_in[7];
  const void* W_UV  = d_in[8];  const void* b_UV  = d_in[9];
  const void* W_UQ  = d_in[10]; const void* b_UQ  = d_in[11];
  const void* W_KR  = d_in[12]; const void* b_KR  = d_in[13];
  const void* W_QR  = d_in[14]; const void* b_QR  = d_in[15];
  const void* W_O   = d_in[16]; const void* b_O   = d_in[17];

  char* wsb = (char*)d_ws;
  size_t off = 0;
  auto allocB = [&](size_t bytes) {
    void* p = wsb + off; off = (off + bytes + 255) & ~(size_t)255; return p;
  };
  int*   flag   = (int*)allocB(4);
  float* fb_dkv = (float*)allocB(512 * 4);
  float* fb_dq  = (float*)allocB(512 * 4);
  float* fb_uk  = (float*)allocB(2048 * 4);
  float* fb_uv  = (float*)allocB(2048 * 4);
  float* fb_uq  = (float*)allocB(2048 * 4);
  float* fb_kr  = (float*)allocB(128 * 4);
  float* fb_qr  = (float*)allocB(128 * 4);
  float* fb_o   = (float*)allocB(2048 * 4);
  bf16* hsb    = (bf16*)allocB((size_t)4096 * 2048 * 2);
  bf16* wt_dkv = (bf16*)allocB((size_t)2048 * 512 * 2);
  bf16* wt_dq  = (bf16*)allocB((size_t)2048 * 512 * 2);
  bf16* wt_uk  = (bf16*)allocB((size_t)512 * 2048 * 2);
  bf16* wt_uv  = (bf16*)allocB((size_t)512 * 2048 * 2);
  bf16* wt_uq  = (bf16*)allocB((size_t)512 * 2048 * 2);
  bf16* wt_kr  = (bf16*)allocB((size_t)2048 * 128 * 2);
  bf16* wt_qr  = (bf16*)allocB((size_t)2048 * 128 * 2);
  bf16* wt_o   = (bf16*)allocB((size_t)2048 * 2048 * 2);
  bf16* c_kv   = (bf16*)allocB((size_t)4096 * 512 * 2);
  bf16* c_q    = (bf16*)allocB((size_t)4096 * 512 * 2);
  bf16* krl    = (bf16*)allocB((size_t)4096 * 128 * 2);
  bf16* qrl    = (bf16*)allocB((size_t)4096 * 128 * 2);
  bf16* k_r    = (bf16*)allocB((size_t)4096 * 128 * 2);
  bf16* q_r    = (bf16*)allocB((size_t)4096 * 128 * 2);
  bf16* k_c    = (bf16*)allocB((size_t)4096 * 2048 * 2);
  bf16* q_c    = (bf16*)allocB((size_t)4096 * 2048 * 2);
  bf16* vT     = (bf16*)allocB((size_t)4096 * 2048 * 2);
  bf16* ctx    = (bf16*)allocB((size_t)4096 * 2048 * 2);

  detect_dtype<<<1, 64, 0, stream>>>(hs, flag);

  // ingest: hs -> bf16, biases -> fp32, weights -> transposed bf16 (N x K)
  convert_hs<<<4096, 256, 0, stream>>>(hs, hsb, flag, 4096 * 2048);
  convert_bias<<<2, 256, 0, stream>>>(b_DKV, fb_dkv, flag, 512);
  convert_bias<<<2, 256, 0, stream>>>(b_DQ,  fb_dq,  flag, 512);
  convert_bias<<<8, 256, 0, stream>>>(b_UK,  fb_uk,  flag, 2048);
  convert_bias<<<8, 256, 0, stream>>>(b_UV,  fb_uv,  flag, 2048);
  convert_bias<<<8, 256, 0, stream>>>(b_UQ,  fb_uq,  flag, 2048);
  convert_bias<<<1, 256, 0, stream>>>(b_KR,  fb_kr,  flag, 128);
  convert_bias<<<1, 256, 0, stream>>>(b_QR,  fb_qr,  flag, 128);
  convert_bias<<<8, 256, 0, stream>>>(b_O,   fb_o,   flag, 2048);
  transpose_any<<<dim3(16, 64), 256, 0, stream>>>(W_DKV, wt_dkv, 2048, 512, flag);
  transpose_any<<<dim3(16, 64), 256, 0, stream>>>(W_DQ,  wt_dq,  2048, 512, flag);
  transpose_any<<<dim3(64, 16), 256, 0, stream>>>(W_UK,  wt_uk,  512, 2048, flag);
  transpose_any<<<dim3(64, 16), 256, 0, stream>>>(W_UV,  wt_uv,  512, 2048, flag);
  transpose_any<<<dim3(64, 16), 256, 0, stream>>>(W_UQ,  wt_uq,  512, 2048, flag);
  transpose_any<<<dim3(4, 64), 256, 0, stream>>>(W_KR,  wt_kr,  2048, 128, flag);
  transpose_any<<<dim3(4, 64), 256, 0, stream>>>(W_QR,  wt_qr,  2048, 128, flag);
  transpose_any<<<dim3(64, 64), 256, 0, stream>>>(W_O,  wt_o, 2048, 2048, flag);

  // projections
  gemm_bt<0, 0><<<dim3(4, 32), 256, 0, stream>>>(hsb, wt_dkv, fb_dkv, c_kv, 4096, 512, 2048, flag);
  gemm_bt<0, 0><<<dim3(4, 32), 256, 0, stream>>>(hsb, wt_dq,  fb_dq,  c_q,  4096, 512, 2048, flag);
  gemm_bt<0, 0><<<dim3(1, 32), 256, 0, stream>>>(hsb, wt_kr,  fb_kr,  krl,  4096, 128, 2048, flag);
  gemm_bt<0, 0><<<dim3(1, 32), 256, 0, stream>>>(hsb, wt_qr,  fb_qr,  qrl,  4096, 128, 2048, flag);
  rope_kernel<<<4096, 64, 0, stream>>>(krl, k_r);
  rope_kernel<<<4096, 64, 0, stream>>>(qrl, q_r);
  gemm_bt<0, 0><<<dim3(16, 32), 256, 0, stream>>>(c_kv, wt_uk, fb_uk, k_c, 4096, 2048, 512, flag);
  gemm_bt<0, 0><<<dim3(16, 32), 256, 0, stream>>>(c_q,  wt_uq, fb_uq, q_c, 4096, 2048, 512, flag);
  gemm_bt<1, 0><<<dim3(16, 32), 256, 0, stream>>>(c_kv, wt_uv, fb_uv, vT,  4096, 2048, 512, flag);

  // attention
  flash_attn<<<dim3(16, 32), 256, 0, stream>>>(q_c, k_c, q_r, k_r, vT, amask, ctx);

  // output projection (dtype-flagged external write)
  gemm_bt<0, 1><<<dim3(16, 32), 256, 0, stream>>>(ctx, wt_o, fb_o, d_out, 4096, 2048, 2048, flag);
}